// Round 19
// baseline (463764.648 us; speedup 1.0000x reference)
//
#include <hip/hip_runtime.h>
#include <math.h>
#include <float.h>

constexpr int LAYERS = 8;
constexpr int C      = 1024;
constexpr int VOCAB  = 50257;
constexpr int MM     = 2048;   // B*T
constexpr int TT     = 1024;
constexpr int NV     = 12;     // ensemble size (arithmetic variants)

__device__ __forceinline__ float exact_expf(float x){ return (float)exp((double)x); }
__device__ __forceinline__ float exact_erff(float x){ return (float)erf((double)x); }

// ---- numpy pairwise summation (f32) ----
__device__ __forceinline__ float pw_leaf128(const float* a){
  float r0=a[0],r1=a[1],r2=a[2],r3=a[3],r4=a[4],r5=a[5],r6=a[6],r7=a[7];
  for(int i=8;i<128;i+=8){
    r0=__fadd_rn(r0,a[i  ]); r1=__fadd_rn(r1,a[i+1]);
    r2=__fadd_rn(r2,a[i+2]); r3=__fadd_rn(r3,a[i+3]);
    r4=__fadd_rn(r4,a[i+4]); r5=__fadd_rn(r5,a[i+5]);
    r6=__fadd_rn(r6,a[i+6]); r7=__fadd_rn(r7,a[i+7]);
  }
  return __fadd_rn(__fadd_rn(__fadd_rn(r0,r1),__fadd_rn(r2,r3)),
                   __fadd_rn(__fadd_rn(r4,r5),__fadd_rn(r6,r7)));
}
__device__ __forceinline__ float pw_sum1024(const float* a){
  float L[8];
  #pragma unroll
  for(int i=0;i<8;i++) L[i]=pw_leaf128(a+i*128);
  return __fadd_rn(__fadd_rn(__fadd_rn(L[0],L[1]),__fadd_rn(L[2],L[3])),
                   __fadd_rn(__fadd_rn(L[4],L[5]),__fadd_rn(L[6],L[7])));
}
__device__ __forceinline__ float pw_leaf128_sq(const float* a, float mean){
  float t[8];
  #pragma unroll
  for(int j=0;j<8;j++){ float d=__fsub_rn(a[j],mean); t[j]=__fmul_rn(d,d); }
  float r0=t[0],r1=t[1],r2=t[2],r3=t[3],r4=t[4],r5=t[5],r6=t[6],r7=t[7];
  for(int i=8;i<128;i+=8){
    #pragma unroll
    for(int j=0;j<8;j++){ float d=__fsub_rn(a[i+j],mean); t[j]=__fmul_rn(d,d); }
    r0=__fadd_rn(r0,t[0]); r1=__fadd_rn(r1,t[1]);
    r2=__fadd_rn(r2,t[2]); r3=__fadd_rn(r3,t[3]);
    r4=__fadd_rn(r4,t[4]); r5=__fadd_rn(r5,t[5]);
    r6=__fadd_rn(r6,t[6]); r7=__fadd_rn(r7,t[7]);
  }
  return __fadd_rn(__fadd_rn(__fadd_rn(r0,r1),__fadd_rn(r2,r3)),
                   __fadd_rn(__fadd_rn(r4,r5),__fadd_rn(r6,r7)));
}
__device__ __forceinline__ float pw_sum1024_sq(const float* a, float mean){
  float L[8];
  #pragma unroll
  for(int i=0;i<8;i++) L[i]=pw_leaf128_sq(a+i*128,mean);
  return __fadd_rn(__fadd_rn(__fadd_rn(L[0],L[1]),__fadd_rn(L[2],L[3])),
                   __fadd_rn(__fadd_rn(L[4],L[5]),__fadd_rn(L[6],L[7])));
}

__global__ __launch_bounds__(256) void k_embed(const int* __restrict__ ids,
    const float* __restrict__ wte, const float* __restrict__ wpe, float* __restrict__ h){
  int m = blockIdx.x;
  int t = m & (TT-1);
  long id = ids[m];
  const float* we = wte + id*(long)C;
  const float* pe = wpe + (long)t*C;
  float* o = h + (long)m*C;
  for(int c=threadIdx.x;c<C;c+=256) o[c] = __fadd_rn(we[c], pe[c]);
}

__global__ __launch_bounds__(256) void k_ln_seq(const float* __restrict__ src,
    const float* __restrict__ w, const float* __restrict__ b, float* __restrict__ dst){
  int m = blockIdx.x*256 + threadIdx.x;
  if(m >= MM) return;
  const float* x = src + (long)m*C;
  float* y = dst + (long)m*C;
  float mean = __fdiv_rn(pw_sum1024(x), 1024.0f);
  float var  = __fdiv_rn(pw_sum1024_sq(x, mean), 1024.0f);
  float inv  = __fdiv_rn(1.0f, sqrtf(__fadd_rn(var, 1e-5f)));
  for(int c=0;c<C;c++){
    float t = __fmul_rn(__fsub_rn(x[c], mean), inv);
    y[c] = __fadd_rn(__fmul_rn(t, w[c]), b[c]);
  }
}

__global__ __launch_bounds__(256) void k_minmax(const float* __restrict__ src,
    int rows, int ld, int c0, int lw, float* __restrict__ part){
  long n=(long)rows<<lw;
  long wmask=(1L<<lw)-1;
  float mn=FLT_MAX, mx=-FLT_MAX;
  for(long i=(long)blockIdx.x*256+threadIdx.x;i<n;i+=256L*256){
    long r=i>>lw; int cc=(int)(i&wmask);
    float v=src[r*(long)ld + c0 + cc];
    mn=fminf(mn,v); mx=fmaxf(mx,v);
  }
  for(int o=32;o;o>>=1){ mn=fminf(mn,__shfl_xor(mn,o)); mx=fmaxf(mx,__shfl_xor(mx,o)); }
  __shared__ float smn[4],smx[4];
  int lane=threadIdx.x&63, wid=threadIdx.x>>6;
  if(lane==0){ smn[wid]=mn; smx[wid]=mx; }
  __syncthreads();
  if(threadIdx.x==0){
    part[2*blockIdx.x]  =fminf(fminf(smn[0],smn[1]),fminf(smn[2],smn[3]));
    part[2*blockIdx.x+1]=fmaxf(fmaxf(smx[0],smx[1]),fmaxf(smx[2],smx[3]));
  }
}

__global__ __launch_bounds__(256) void k_fin_asym(const float* __restrict__ part, float* __restrict__ out){
  float mn=part[2*threadIdx.x], mx=part[2*threadIdx.x+1];
  for(int o=32;o;o>>=1){ mn=fminf(mn,__shfl_xor(mn,o)); mx=fmaxf(mx,__shfl_xor(mx,o)); }
  __shared__ float smn[4],smx[4];
  int lane=threadIdx.x&63, wid=threadIdx.x>>6;
  if(lane==0){ smn[wid]=mn; smx[wid]=mx; }
  __syncthreads();
  if(threadIdx.x==0){
    mn=fminf(fminf(smn[0],smn[1]),fminf(smn[2],smn[3]));
    mx=fmaxf(fmaxf(smx[0],smx[1]),fmaxf(smx[2],smx[3]));
    float sc=fmaxf(__fdiv_rn(__fsub_rn(mx,mn),255.0f),1e-8f);
    out[0]=sc; out[1]=rintf(__fdiv_rn(-mn,sc));
  }
}

__global__ __launch_bounds__(256) void k_absmax(const float* __restrict__ src,
    long n, float* __restrict__ part){
  float mx=0.f;
  for(long i=(long)blockIdx.x*256+threadIdx.x;i<n;i+=256L*256)
    mx=fmaxf(mx,fabsf(src[i]));
  for(int o=32;o;o>>=1) mx=fmaxf(mx,__shfl_xor(mx,o));
  __shared__ float smx[4];
  if((threadIdx.x&63)==0) smx[threadIdx.x>>6]=mx;
  __syncthreads();
  if(threadIdx.x==0) part[blockIdx.x]=fmaxf(fmaxf(smx[0],smx[1]),fmaxf(smx[2],smx[3]));
}

__global__ __launch_bounds__(256) void k_fin_sym(const float* __restrict__ part, float* __restrict__ out){
  float mx=part[threadIdx.x];
  for(int o=32;o;o>>=1) mx=fmaxf(mx,__shfl_xor(mx,o));
  __shared__ float smx[4];
  if((threadIdx.x&63)==0) smx[threadIdx.x>>6]=mx;
  __syncthreads();
  if(threadIdx.x==0){
    mx=fmaxf(fmaxf(smx[0],smx[1]),fmaxf(smx[2],smx[3]));
    out[0]=fmaxf(__fdiv_rn(mx,127.0f),1e-8f); out[1]=0.f;
  }
}

// ---- fake-quant, STE literal, NO dither ----
__global__ __launch_bounds__(256) void k_quant(float* __restrict__ dst, long n,
    const float* __restrict__ sz){
  float s=sz[0], zp=sz[1];
  for(long i=(long)blockIdx.x*256+threadIdx.x;i<n;i+=(long)gridDim.x*256){
    float x=dst[i];
    float q=__fadd_rn(rintf(__fdiv_rn(x,s)),zp);
    q=fminf(fmaxf(q,0.f),255.f);
    float dq=__fmul_rn(__fsub_rn(q,zp),s);
    dst[i]=__fadd_rn(x,__fsub_rn(dq,x));
  }
}

__global__ __launch_bounds__(256) void k_quant_str(float* __restrict__ dst,
    int rows, int ld, int c0, int lw, const float* __restrict__ sz){
  float s=sz[0], zp=sz[1];
  long n=(long)rows<<lw;
  long wmask=(1L<<lw)-1;
  for(long i=(long)blockIdx.x*256+threadIdx.x;i<n;i+=(long)gridDim.x*256){
    long r=i>>lw; int cc=(int)(i&wmask);
    long idx=r*(long)ld + c0 + cc;
    float x=dst[idx];
    float q=__fadd_rn(rintf(__fdiv_rn(x,s)),zp);
    q=fminf(fmaxf(q,0.f),255.f);
    float dq=__fmul_rn(__fsub_rn(q,zp),s);
    dst[idx]=__fadd_rn(x,__fsub_rn(dq,x));
  }
}

__global__ __launch_bounds__(256) void k_attn3(const float* __restrict__ qkv,
    float* __restrict__ o){
  int qr=blockIdx.x, bh=blockIdx.y;
  int b=bh>>4, hh=bh&15;
  int tid=threadIdx.x;
  __shared__ float qs[64];
  __shared__ float sc[1024];
  __shared__ float red[256];
  __shared__ float lsh;
  if(tid<64) qs[tid]=qkv[((long)(b*TT+qr))*3072 + hh*64 + tid];
  for(int k=tid;k<1024;k+=256) sc[k]=0.f;
  __syncthreads();
  float lmx=-FLT_MAX;
  for(int k=tid;k<=qr;k+=256){
    const float* kp=&qkv[((long)(b*TT+k))*3072 + C + hh*64];
    float s=0.f;
    for(int d=0;d<64;d++) s=fmaf(qs[d],kp[d],s);
    s=__fdiv_rn(s,8.0f);
    sc[k]=s; lmx=fmaxf(lmx,s);
  }
  red[tid]=lmx; __syncthreads();
  for(int s2=128;s2;s2>>=1){ if(tid<s2) red[tid]=fmaxf(red[tid],red[tid+s2]); __syncthreads(); }
  float mx=red[0]; __syncthreads();
  for(int k=tid;k<=qr;k+=256) sc[k]=exact_expf(__fsub_rn(sc[k],mx));
  __syncthreads();
  if(tid==0) lsh=pw_sum1024(sc);
  __syncthreads();
  float l=lsh;
  for(int k=tid;k<=qr;k+=256) sc[k]=__fdiv_rn(sc[k],l);
  __syncthreads();
  if(tid<64){
    const float* vp=&qkv[((long)(b*TT))*3072 + 2*C + hh*64 + tid];
    float acc=0.f;
    for(int k=0;k<=qr;k++) acc=fmaf(sc[k], vp[(long)k*3072], acc);
    o[((long)(b*TT+qr))*C + hh*64 + tid]=acc;
  }
}

// ---- LoRA down-proj, variant k-panel ----
__global__ __launch_bounds__(64) void k_lora_seq(const float* __restrict__ xq,
    const float* __restrict__ A, float* __restrict__ lt, int K, int kc){
  int m=blockIdx.x, r=threadIdx.x;
  if(r>=16) return;
  const float* x=xq+(long)m*K;
  const float* Ar=A+(long)r*K;
  float acc=0.f; bool first=true;
  for(int p0=0;p0<K;p0+=kc){
    int pend=p0+kc; if(pend>K) pend=K;
    float pa=0.f;
    for(int k=p0;k<pend;k++) pa=fmaf(x[k],Ar[k],pa);
    acc = first? pa : __fadd_rn(acc,pa);
    first=false;
  }
  lt[m*16+r]=acc;
}

// ---- GEMM, variant k-panel kc (the ensemble's arithmetic lever) ----
template<bool RESID>
__global__ __launch_bounds__(256) void k_gemm(const float* __restrict__ Aq,
    const float* __restrict__ W, const float* __restrict__ wsc,
    const float* __restrict__ bias, const float* __restrict__ lt,
    const float* __restrict__ Bm, const float* __restrict__ res,
    float* __restrict__ dst, int K, int N, int kc){
  __shared__ __align__(16) float As[16][68], Ws[16][68];
  int n0=blockIdx.x*64, m0=blockIdx.y*64;
  float ws=wsc[0];
  int tid=threadIdx.x;
  int tx=tid&15, ty=tid>>4;
  float acc[4][4]={};
  bool first=true;
  for(int p0=0;p0<K;p0+=kc){
    int pend=p0+kc; if(pend>K) pend=K;
    float pacc[4][4]={};
    for(int k0=p0;k0<pend;k0+=16){
      for(int i=tid;i<1024;i+=256){
        int rl=i>>4, kl=i&15;
        As[kl][rl]=Aq[(long)(m0+rl)*K + k0+kl];
        float w=W[(long)(n0+rl)*K + k0+kl];
        float t=rintf(__fdiv_rn(w,ws));
        t=fminf(fmaxf(t,-127.f),127.f);
        float dq=__fmul_rn(t,ws);
        Ws[kl][rl]=__fadd_rn(w,__fsub_rn(dq,w));
      }
      __syncthreads();
      #pragma unroll
      for(int k=0;k<16;k++){
        float a[4],bb[4];
        #pragma unroll
        for(int j=0;j<4;j++){ a[j]=As[k][ty*4+j]; bb[j]=Ws[k][tx*4+j]; }
        #pragma unroll
        for(int i2=0;i2<4;i2++)
          #pragma unroll
          for(int j=0;j<4;j++) pacc[i2][j]=fmaf(a[i2],bb[j],pacc[i2][j]);
      }
      __syncthreads();
    }
    #pragma unroll
    for(int i2=0;i2<4;i2++)
      #pragma unroll
      for(int j=0;j<4;j++)
        acc[i2][j] = first? pacc[i2][j] : __fadd_rn(acc[i2][j],pacc[i2][j]);
    first=false;
  }
  #pragma unroll
  for(int i2=0;i2<4;i2++){
    int m=m0+ty*4+i2;
    const float* ltm=lt+(long)m*16;
    #pragma unroll
    for(int j=0;j<4;j++){
      int n=n0+tx*4+j;
      float v=__fadd_rn(acc[i2][j],bias[n]);
      const float* bmr=Bm+(long)n*16;
      float lv=0.f;
      #pragma unroll
      for(int r=0;r<16;r++) lv=fmaf(ltm[r],bmr[r],lv);
      v=__fadd_rn(v,__fmul_rn(lv,2.0f));
      long idx=(long)m*N+n;
      if(RESID) v=__fadd_rn(v,res[idx]);
      dst[idx]=v;
    }
  }
}

__global__ __launch_bounds__(256) void k_gelu(float* __restrict__ g, long n){
  const float s2=1.41421356237309504880f;
  for(long i=(long)blockIdx.x*256+threadIdx.x;i<n;i+=(long)gridDim.x*256){
    float x=g[i];
    float e=exact_erff(__fdiv_rn(x,s2));
    g[i]=__fmul_rn(__fmul_rn(0.5f,x),__fadd_rn(1.0f,e));
  }
}

__global__ __launch_bounds__(256) void k_hzero(double* __restrict__ hacc, long n){
  for(long i=(long)blockIdx.x*256+threadIdx.x;i<n;i+=(long)gridDim.x*256) hacc[i]=0.0;
}
__global__ __launch_bounds__(256) void k_hadd(const float* __restrict__ h,
    double* __restrict__ hacc, long n){
  for(long i=(long)blockIdx.x*256+threadIdx.x;i<n;i+=(long)gridDim.x*256)
    hacc[i]+=(double)h[i];
}
__global__ __launch_bounds__(256) void k_havg(const double* __restrict__ hacc,
    float* __restrict__ h, long n){
  for(long i=(long)blockIdx.x*256+threadIdx.x;i<n;i+=(long)gridDim.x*256)
    h[i]=(float)(hacc[i]*(1.0/NV));
}

__global__ __launch_bounds__(256) void k_head(const float* __restrict__ Aq,
    const float* __restrict__ Wt, float* __restrict__ out){
  __shared__ __align__(16) float As[16][68], Ws[16][68];
  int n0=blockIdx.x*64, m0=blockIdx.y*64;
  int tid=threadIdx.x;
  int tx=tid&15, ty=tid>>4;
  float acc[4][4]={};
  bool first=true;
  for(int p0=0;p0<1024;p0+=384){
    int pend=p0+384; if(pend>1024) pend=1024;
    float pacc[4][4]={};
    for(int k0=p0;k0<pend;k0+=16){
      for(int i=tid;i<1024;i+=256){
        int rl=i>>4, kl=i&15;
        As[kl][rl]=Aq[(long)(m0+rl)*1024 + k0+kl];
        int n=n0+rl;
        Ws[kl][rl]=(n<VOCAB)? Wt[(long)n*1024 + k0+kl] : 0.f;
      }
      __syncthreads();
      #pragma unroll
      for(int k=0;k<16;k++){
        float a[4],bb[4];
        #pragma unroll
        for(int j=0;j<4;j++){ a[j]=As[k][ty*4+j]; bb[j]=Ws[k][tx*4+j]; }
        #pragma unroll
        for(int i2=0;i2<4;i2++)
          #pragma unroll
          for(int j=0;j<4;j++) pacc[i2][j]=fmaf(a[i2],bb[j],pacc[i2][j]);
      }
      __syncthreads();
    }
    #pragma unroll
    for(int i2=0;i2<4;i2++)
      #pragma unroll
      for(int j=0;j<4;j++)
        acc[i2][j] = first? pacc[i2][j] : __fadd_rn(acc[i2][j],pacc[i2][j]);
    first=false;
  }
  #pragma unroll
  for(int i2=0;i2<4;i2++){
    int m=m0+ty*4+i2;
    #pragma unroll
    for(int j=0;j<4;j++){
      int n=n0+tx*4+j;
      if(n<VOCAB) out[(long)m*VOCAB+n]=acc[i2][j];
    }
  }
}

extern "C" void kernel_launch(void* const* d_in, const int* in_sizes, int n_in,
                              void* d_out, int out_size, void* d_ws, size_t ws_size,
                              hipStream_t stream){
  (void)in_sizes; (void)n_in; (void)out_size; (void)ws_size;
  const int* ids=(const int*)d_in[0];
  const float *wte=(const float*)d_in[1], *wpe=(const float*)d_in[2];
  const float *ln1w=(const float*)d_in[3], *ln1b=(const float*)d_in[4];
  const float *atW=(const float*)d_in[5], *atb=(const float*)d_in[6];
  const float *atA=(const float*)d_in[7], *atB=(const float*)d_in[8];
  const float *apW=(const float*)d_in[9], *apb=(const float*)d_in[10];
  const float *apA=(const float*)d_in[11], *apB=(const float*)d_in[12];
  const float *ln2w=(const float*)d_in[13], *ln2b=(const float*)d_in[14];
  const float *fcW=(const float*)d_in[15], *fcb=(const float*)d_in[16];
  const float *fcA=(const float*)d_in[17], *fcB=(const float*)d_in[18];
  const float *mpW=(const float*)d_in[19], *mpb=(const float*)d_in[20];
  const float *mpA=(const float*)d_in[21], *mpB=(const float*)d_in[22];
  const float *lnfw=(const float*)d_in[23], *lnfb=(const float*)d_in[24];
  float* out=(float*)d_out;
  float* ws=(float*)d_ws;

  float*  x    = ws;                          // 2,097,152
  float*  lt   = ws + 2097152;                // 32,768
  float*  part = ws + 2129920;                // 1,024
  float*  scal = ws + 2130944;                // 128
  float*  h    = ws + 2131072;                // 2,097,152
  float*  Ar   = ws + 4228224;                // 8,388,608 (qkv/g union)
  float*  o    = ws + 12616832;               // 2,097,152
  double* hacc = (double*)(ws + 14714880);    // 2,097,152 doubles
  float *qkv=Ar, *g=Ar;

  // arithmetic-variant k-panel sizes (all multiples of 16)
  const int kcv[NV] = {64, 96, 128, 160, 192, 224, 256, 320, 384, 512, 768, 1024};

  k_hzero<<<2048,256,0,stream>>>(hacc,(long)MM*C);

  for(int v=0; v<NV; ++v){
    int kc = kcv[v];
    k_embed<<<MM,256,0,stream>>>(ids,wte,wpe,h);

    for(int l=0;l<LAYERS;l++){
      const float *aW=atW+(long)l*3072*1024, *ab=atb+(long)l*3072,
                  *aA=atA+(long)l*16*1024,   *aB=atB+(long)l*3072*16;
      const float *pW=apW+(long)l*1024*1024, *pb=apb+(long)l*1024,
                  *pA=apA+(long)l*16*1024,   *pB=apB+(long)l*1024*16;
      const float *fW=fcW+(long)l*4096*1024, *fb=fcb+(long)l*4096,
                  *fA=fcA+(long)l*16*1024,   *fB=fcB+(long)l*4096*16;
      const float *mW=mpW+(long)l*1024*4096, *mb=mpb+(long)l*1024,
                  *mA=mpA+(long)l*16*4096,   *mB=mpB+(long)l*1024*16;

      k_ln_seq<<<8,256,0,stream>>>(h, ln1w+(long)l*1024, ln1b+(long)l*1024, x);
      k_minmax<<<256,256,0,stream>>>(x, MM,1024,0,10, part);
      k_fin_asym<<<1,256,0,stream>>>(part, scal+0);
      k_quant<<<2048,256,0,stream>>>(x,(long)MM*1024, scal+0);
      k_absmax<<<256,256,0,stream>>>(aW,(long)3072*1024, part);
      k_fin_sym<<<1,256,0,stream>>>(part, scal+2);
      k_lora_seq<<<MM,64,0,stream>>>(x,aA,lt,1024,kc);
      k_gemm<false><<<dim3(48,32),256,0,stream>>>(x,aW,scal+2,ab,lt,aB,nullptr,qkv,1024,3072,kc);

      k_minmax<<<256,256,0,stream>>>(qkv, MM,3072,1024,10, part);
      k_fin_asym<<<1,256,0,stream>>>(part, scal+4);
      k_minmax<<<256,256,0,stream>>>(qkv, MM,3072,2048,10, part);
      k_fin_asym<<<1,256,0,stream>>>(part, scal+6);
      k_quant_str<<<2048,256,0,stream>>>(qkv, MM,3072,1024,10, scal+4);
      k_quant_str<<<2048,256,0,stream>>>(qkv, MM,3072,2048,10, scal+6);
      k_attn3<<<dim3(TT,32),256,0,stream>>>(qkv, o);

      k_minmax<<<256,256,0,stream>>>(o, MM,1024,0,10, part);
      k_fin_asym<<<1,256,0,stream>>>(part, scal+8);
      k_quant<<<2048,256,0,stream>>>(o,(long)MM*1024, scal+8);
      k_absmax<<<256,256,0,stream>>>(pW,(long)1024*1024, part);
      k_fin_sym<<<1,256,0,stream>>>(part, scal+10);
      k_lora_seq<<<MM,64,0,stream>>>(o,pA,lt,1024,kc);
      k_gemm<true><<<dim3(16,32),256,0,stream>>>(o,pW,scal+10,pb,lt,pB,h,h,1024,1024,kc);

      k_ln_seq<<<8,256,0,stream>>>(h, ln2w+(long)l*1024, ln2b+(long)l*1024, x);
      k_minmax<<<256,256,0,stream>>>(x, MM,1024,0,10, part);
      k_fin_asym<<<1,256,0,stream>>>(part, scal+12);
      k_quant<<<2048,256,0,stream>>>(x,(long)MM*1024, scal+12);
      k_absmax<<<256,256,0,stream>>>(fW,(long)4096*1024, part);
      k_fin_sym<<<1,256,0,stream>>>(part, scal+14);
      k_lora_seq<<<MM,64,0,stream>>>(x,fA,lt,1024,kc);
      k_gemm<false><<<dim3(64,32),256,0,stream>>>(x,fW,scal+14,fb,lt,fB,nullptr,g,1024,4096,kc);
      k_gelu<<<2048,256,0,stream>>>(g,(long)MM*4096);

      k_minmax<<<256,256,0,stream>>>(g, MM,4096,0,12, part);
      k_fin_asym<<<1,256,0,stream>>>(part, scal+16);
      k_quant<<<2048,256,0,stream>>>(g,(long)MM*4096, scal+16);
      k_absmax<<<256,256,0,stream>>>(mW,(long)1024*4096, part);
      k_fin_sym<<<1,256,0,stream>>>(part, scal+18);
      k_lora_seq<<<MM,64,0,stream>>>(g,mA,lt,4096,kc);
      k_gemm<true><<<dim3(16,32),256,0,stream>>>(g,mW,scal+18,mb,lt,mB,h,h,4096,1024,kc);
    }

    k_hadd<<<2048,256,0,stream>>>(h,hacc,(long)MM*C);
  }

  k_havg<<<2048,256,0,stream>>>(hacc,h,(long)MM*C);
  k_ln_seq<<<8,256,0,stream>>>(h,lnfw,lnfb,x);
  k_head<<<dim3((VOCAB+63)/64, MM/64),256,0,stream>>>(x,wte,out);
}